// Round 1
// baseline (834.478 us; speedup 1.0000x reference)
//
#include <hip/hip_runtime.h>
#include <hip/hip_bf16.h>

#define L_SEQ 2048
#define BSZ 2
#define DMODEL 1024
#define NHEAD 16
#define NROWS 4096  // L*BS

typedef __attribute__((ext_vector_type(8))) short bf16x8;
typedef __attribute__((ext_vector_type(4))) float f32x4;
typedef unsigned short u16;
typedef unsigned int u32;

__device__ __forceinline__ u16 f2bf(float x) {
  union { __hip_bfloat16 h; u16 u; } cv;
  cv.h = __float2bfloat16(x);
  return cv.u;
}

__device__ __forceinline__ void async16(void* lds, const void* g) {
  __builtin_amdgcn_global_load_lds(
      (const __attribute__((address_space(1))) void*)g,
      (__attribute__((address_space(3))) void*)lds, 16, 0, 0);
}

// ---------------- converts ----------------
__global__ __launch_bounds__(256) void cvt_kernel(const float* __restrict__ s,
                                                  u16* __restrict__ d, int n) {
  int i = (blockIdx.x * 256 + threadIdx.x) * 4;
  if (i >= n) return;
  float4 v = *(const float4*)(s + i);
  ushort4 o;
  o.x = f2bf(v.x); o.y = f2bf(v.y); o.z = f2bf(v.z); o.w = f2bf(v.w);
  *(ushort4*)(d + i) = o;
}

// V (4096x1024 f32) -> right half of combined (4096x2048 bf16)
__global__ __launch_bounds__(256) void cvtV_kernel(const float* __restrict__ s,
                                                   u16* __restrict__ comb) {
  int i = (blockIdx.x * 256 + threadIdx.x) * 4;
  if (i >= NROWS * DMODEL) return;
  int r = i >> 10, c = i & 1023;
  float4 v = *(const float4*)(s + i);
  ushort4 o;
  o.x = f2bf(v.x); o.y = f2bf(v.y); o.z = f2bf(v.z); o.w = f2bf(v.w);
  *(ushort4*)(comb + (size_t)r * 2048 + 1024 + c) = o;
}

// ---------------- GEMM: C(MxN) = A(MxK) @ B(NxK)^T, bf16 in, fp32 acc -------
__global__ __launch_bounds__(256) void gemm_bt(
    const u16* __restrict__ A, const u16* __restrict__ B,
    const float* __restrict__ bias, float scale,
    u16* __restrict__ Cb, float* __restrict__ Cf, float* __restrict__ ksq_out,
    int M, int N, int K) {
  __shared__ u16 As[128 * 64];
  __shared__ u16 Bs[128 * 64];
  const int tid = threadIdx.x;
  const int w = tid >> 6, lane = tid & 63;
  const int quad = lane >> 4, m16 = lane & 15;
  const int wr = w >> 1, wc = w & 1;
  const int m0 = blockIdx.y * 128, n0 = blockIdx.x * 128;
  f32x4 acc[4][4] = {};

  for (int kt = 0; kt < K; kt += 64) {
    __syncthreads();
#pragma unroll
    for (int j = 0; j < 4; ++j) {
      int chunk = (w * 4 + j) * 64 + lane;  // 0..1023, 16B each
      int row = chunk >> 3, kc = chunk & 7;
      async16(As + (size_t)(w * 4 + j) * 512,
              A + (size_t)(m0 + row) * K + kt + kc * 8);
      async16(Bs + (size_t)(w * 4 + j) * 512,
              B + (size_t)(n0 + row) * K + kt + kc * 8);
    }
    __syncthreads();
#pragma unroll
    for (int kk = 0; kk < 2; ++kk) {
      bf16x8 af[4], bfr[4];
#pragma unroll
      for (int i = 0; i < 4; ++i)
        af[i] = *(const bf16x8*)(As + (wr * 64 + i * 16 + m16) * 64 + kk * 32 + quad * 8);
#pragma unroll
      for (int j = 0; j < 4; ++j)
        bfr[j] = *(const bf16x8*)(Bs + (wc * 64 + j * 16 + m16) * 64 + kk * 32 + quad * 8);
#pragma unroll
      for (int i = 0; i < 4; ++i)
#pragma unroll
        for (int j = 0; j < 4; ++j)
          acc[i][j] = __builtin_amdgcn_mfma_f32_16x16x32_bf16(af[i], bfr[j], acc[i][j], 0, 0, 0);
    }
  }

#pragma unroll
  for (int i = 0; i < 4; ++i) {
    int R0 = m0 + wr * 64 + i * 16 + quad * 4;
    float ksq_part[4] = {0.f, 0.f, 0.f, 0.f};
#pragma unroll
    for (int j = 0; j < 4; ++j) {
      int C = n0 + wc * 64 + j * 16 + m16;
      float bv = bias ? bias[C] : 0.0f;
#pragma unroll
      for (int r = 0; r < 4; ++r) {
        float v = (acc[i][j][r] + bv) * scale;
        size_t idx = (size_t)(R0 + r) * N + C;
        if (Cb) Cb[idx] = f2bf(v);
        if (Cf) Cf[idx] = v;
        if (ksq_out) ksq_part[r] += v * v;
      }
    }
    if (ksq_out) {
#pragma unroll
      for (int r = 0; r < 4; ++r) {
        float t = ksq_part[r];
        t += __shfl_xor(t, 1); t += __shfl_xor(t, 2);
        t += __shfl_xor(t, 4); t += __shfl_xor(t, 8);
        if (m16 == 0) {
          int R = R0 + r;
          int bb = R & 1, l = R >> 1;
          int h = (n0 + wc * 64) >> 6;
          ksq_out[(size_t)(bb * NHEAD + h) * L_SEQ + l] = t;
        }
      }
    }
  }
}

// ---------------- attention ----------------
// block: 64 q-rows of one (b,h). scores = qp.kp - ksq (scales pre-folded).
// LDS layouts are XOR-swizzled on the 16B granule to kill bank conflicts:
//   Ks/Qs: granule(row,kc) holds global granule (row, kc ^ (row&7))
//          (async16 dest is linear; source pre-swizzled per rule "both-sides")
//   Vst [d][key]: key-granule ^= ((d>>3) ^ (d&7)) & 7   (write AND read decorrelated)
//   Ps  [qrow][col]: col-granule ^= qrow & 7
__global__ __launch_bounds__(256) void attn_kernel(
    const u16* __restrict__ qp, const u16* __restrict__ kp,
    const float* __restrict__ ksqg, const u16* __restrict__ comb_v,
    u16* __restrict__ comb_o, float* __restrict__ attn_out) {
  __shared__ u16 Qs[64 * 64];
  __shared__ u16 Ks[64 * 64];
  __shared__ u16 Vst[64 * 64];  // [d][key], swizzled
  __shared__ u16 Ps[4 * 16 * 64];
  __shared__ float ksq_s[64];
  const int tid = threadIdx.x;
  const int w = tid >> 6, lane = tid & 63;
  const int quad = lane >> 4, m16 = lane & 15;
  const int qt = blockIdx.x, bh = blockIdx.y;
  const int b = bh >> 4, h = bh & 15;
  const int q0 = qt * 64;
  const int rsw = (m16 & 7) << 3;  // read-side granule xor, in elements

#pragma unroll
  for (int j = 0; j < 2; ++j) {
    int chunk = (w * 2 + j) * 64 + lane;  // 0..511
    int row = chunk >> 3, kc = chunk & 7;
    int kcs = kc ^ (row & 7);  // pre-swizzled source granule
    async16(Qs + (size_t)(w * 2 + j) * 512,
            qp + (size_t)((q0 + row) * 2 + b) * 1024 + h * 64 + kcs * 8);
  }
  __syncthreads();
  bf16x8 aq0 = *(const bf16x8*)(Qs + (w * 16 + m16) * 64 + ((quad * 8) ^ rsw));
  bf16x8 aq1 = *(const bf16x8*)(Qs + (w * 16 + m16) * 64 + ((32 + quad * 8) ^ rsw));

  // pass A: row sums of exp(s). (s <= ||q||^2 ~ 2.5, no max needed)
  float lsum[4] = {0.f, 0.f, 0.f, 0.f};
  for (int kt = 0; kt < 32; ++kt) {
    __syncthreads();
#pragma unroll
    for (int j = 0; j < 2; ++j) {
      int chunk = (w * 2 + j) * 64 + lane;
      int row = chunk >> 3, kc = chunk & 7;
      int kcs = kc ^ (row & 7);
      async16(Ks + (size_t)(w * 2 + j) * 512,
              kp + (size_t)((kt * 64 + row) * 2 + b) * 1024 + h * 64 + kcs * 8);
    }
    if (tid < 64) ksq_s[tid] = ksqg[(size_t)bh * L_SEQ + kt * 64 + tid];
    __syncthreads();
#pragma unroll
    for (int j = 0; j < 4; ++j) {
      const u16* kr = Ks + (j * 16 + m16) * 64;
      bf16x8 bk0 = *(const bf16x8*)(kr + ((quad * 8) ^ rsw));
      bf16x8 bk1 = *(const bf16x8*)(kr + ((32 + quad * 8) ^ rsw));
      f32x4 s4 = {0.f, 0.f, 0.f, 0.f};
      __builtin_amdgcn_s_setprio(1);
      s4 = __builtin_amdgcn_mfma_f32_16x16x32_bf16(aq0, bk0, s4, 0, 0, 0);
      s4 = __builtin_amdgcn_mfma_f32_16x16x32_bf16(aq1, bk1, s4, 0, 0, 0);
      __builtin_amdgcn_s_setprio(0);
      float kq = ksq_s[j * 16 + m16];
#pragma unroll
      for (int r = 0; r < 4; ++r) lsum[r] += __expf(s4[r] - kq);
    }
  }
#pragma unroll
  for (int r = 0; r < 4; ++r) {
    float t = lsum[r];
    t += __shfl_xor(t, 1); t += __shfl_xor(t, 2);
    t += __shfl_xor(t, 4); t += __shfl_xor(t, 8);
    lsum[r] = 1.0f / t;
  }

  // pass B: recompute S, write attn, P@V
  f32x4 o[4] = {};
  for (int kt = 0; kt < 32; ++kt) {
    __syncthreads();
#pragma unroll
    for (int j = 0; j < 2; ++j) {
      int chunk = (w * 2 + j) * 64 + lane;
      int row = chunk >> 3, kc = chunk & 7;
      int kcs = kc ^ (row & 7);
      async16(Ks + (size_t)(w * 2 + j) * 512,
              kp + (size_t)((kt * 64 + row) * 2 + b) * 1024 + h * 64 + kcs * 8);
    }
#pragma unroll
    for (int it = 0; it < 2; ++it) {  // V transpose: [key][d] -> [d][key] (swizzled)
      int chunk = it * 256 + tid;
      int key = chunk >> 3, dc = chunk & 7;
      const u16* gp = comb_v + (size_t)((kt * 64 + key) * 2 + b) * 2048 + 1024 + h * 64 + dc * 8;
      uint4 u = *(const uint4*)gp;
      u32 parts[4] = {u.x, u.y, u.z, u.w};
#pragma unroll
      for (int q2 = 0; q2 < 4; ++q2) {
        int dA = dc * 8 + q2 * 2;      // even d
        int dB = dA + 1;               // odd d
        int kxA = key ^ (((dc ^ (dA & 7)) & 7) << 3);
        int kxB = key ^ (((dc ^ (dB & 7)) & 7) << 3);
        Vst[dA * 64 + kxA] = (u16)(parts[q2] & 0xffffu);
        Vst[dB * 64 + kxB] = (u16)(parts[q2] >> 16);
      }
    }
    if (tid < 64) ksq_s[tid] = ksqg[(size_t)bh * L_SEQ + kt * 64 + tid];
    __syncthreads();
#pragma unroll
    for (int j = 0; j < 4; ++j) {
      const u16* kr = Ks + (j * 16 + m16) * 64;
      bf16x8 bk0 = *(const bf16x8*)(kr + ((quad * 8) ^ rsw));
      bf16x8 bk1 = *(const bf16x8*)(kr + ((32 + quad * 8) ^ rsw));
      f32x4 s4 = {0.f, 0.f, 0.f, 0.f};
      __builtin_amdgcn_s_setprio(1);
      s4 = __builtin_amdgcn_mfma_f32_16x16x32_bf16(aq0, bk0, s4, 0, 0, 0);
      s4 = __builtin_amdgcn_mfma_f32_16x16x32_bf16(aq1, bk1, s4, 0, 0, 0);
      __builtin_amdgcn_s_setprio(0);
      float kq = ksq_s[j * 16 + m16];
      size_t abase = ((size_t)bh * L_SEQ + q0 + w * 16 + quad * 4) * L_SEQ + kt * 64 + j * 16 + m16;
#pragma unroll
      for (int r = 0; r < 4; ++r) {
        float p = __expf(s4[r] - kq) * lsum[r];
        attn_out[abase + (size_t)r * L_SEQ] = p;
        int qrow = quad * 4 + r;
        int col = j * 16 + m16;
        Ps[w * 1024 + qrow * 64 + (col ^ ((qrow & 7) << 3))] = f2bf(p);
      }
    }
    __syncthreads();
#pragma unroll
    for (int kk = 0; kk < 2; ++kk) {
      bf16x8 pa = *(const bf16x8*)(Ps + w * 1024 + m16 * 64 +
                                   (((kk * 32 + quad * 8)) ^ rsw));
      __builtin_amdgcn_s_setprio(1);
#pragma unroll
      for (int j2 = 0; j2 < 4; ++j2) {
        int d = j2 * 16 + m16;
        int vx = (((d >> 3) ^ (d & 7)) & 7) << 3;
        bf16x8 bv = *(const bf16x8*)(Vst + d * 64 + ((kk * 32 + quad * 8) ^ vx));
        o[j2] = __builtin_amdgcn_mfma_f32_16x16x32_bf16(pa, bv, o[j2], 0, 0, 0);
      }
      __builtin_amdgcn_s_setprio(0);
    }
  }
#pragma unroll
  for (int j2 = 0; j2 < 4; ++j2) {
#pragma unroll
    for (int r = 0; r < 4; ++r) {
      int qrow = q0 + w * 16 + quad * 4 + r;
      comb_o[(size_t)(qrow * 2 + b) * 2048 + h * 64 + j2 * 16 + m16] = f2bf(o[j2][r]);
    }
  }
}

extern "C" void kernel_launch(void* const* d_in, const int* in_sizes, int n_in,
                              void* d_out, int out_size, void* d_ws, size_t ws_size,
                              hipStream_t stream) {
  const float* Q  = (const float*)d_in[0];
  const float* K  = (const float*)d_in[1];
  const float* V  = (const float*)d_in[2];
  const float* WQ = (const float*)d_in[3];
  const float* bQ = (const float*)d_in[4];
  const float* WK = (const float*)d_in[5];
  const float* bK = (const float*)d_in[6];
  const float* Wp = (const float*)d_in[7];
  const float* bp = (const float*)d_in[8];
  float* proj_out = (float*)d_out;
  float* attn_out = proj_out + (size_t)NROWS * DMODEL;

  char* ws = (char*)d_ws;
  const size_t MB = 1u << 20;
  u16* Qb   = (u16*)(ws + 0 * MB);    // 8 MB
  u16* Kb   = (u16*)(ws + 8 * MB);    // 8 MB
  u16* WQb  = (u16*)(ws + 16 * MB);   // 2 MB
  u16* WKb  = (u16*)(ws + 18 * MB);   // 2 MB
  u16* Wpb  = (u16*)(ws + 20 * MB);   // 4 MB
  u16* qpb  = (u16*)(ws + 24 * MB);   // 8 MB (pre-scaled by 0.25)
  u16* kpb  = (u16*)(ws + 32 * MB);   // 8 MB
  u16* comb = (u16*)(ws + 40 * MB);   // 16 MB (4096x2048: [attn_out | V])
  float* ksqb = (float*)(ws + 56 * MB);  // 256 KB

  cvt_kernel<<<4096, 256, 0, stream>>>(Q, Qb, NROWS * DMODEL);
  cvt_kernel<<<4096, 256, 0, stream>>>(K, Kb, NROWS * DMODEL);
  cvt_kernel<<<1024, 256, 0, stream>>>(WQ, WQb, DMODEL * DMODEL);
  cvt_kernel<<<1024, 256, 0, stream>>>(WK, WKb, DMODEL * DMODEL);
  cvt_kernel<<<2048, 256, 0, stream>>>(Wp, Wpb, DMODEL * 2 * DMODEL);
  cvtV_kernel<<<4096, 256, 0, stream>>>(V, comb);

  // qp = 0.25*(Q @ WQ^T + bQ)   [score = qp.kp - ksq]
  gemm_bt<<<dim3(8, 32), 256, 0, stream>>>(Qb, WQb, bQ, 0.25f, qpb, nullptr, nullptr,
                                           NROWS, DMODEL, DMODEL);
  // kp = K @ WK^T + bK, plus fp32 ksq per (b,h,l)
  gemm_bt<<<dim3(8, 32), 256, 0, stream>>>(Kb, WKb, bK, 1.0f, kpb, nullptr, ksqb,
                                           NROWS, DMODEL, DMODEL);
  attn_kernel<<<dim3(32, 32), 256, 0, stream>>>(qpb, kpb, ksqb, comb, comb, attn_out);
  // proj = [out|V] @ Wp^T + bp
  gemm_bt<<<dim3(8, 32), 256, 0, stream>>>(comb, Wpb, bp, 1.0f, nullptr, proj_out, nullptr,
                                           NROWS, DMODEL, 2 * DMODEL);
}

// Round 3
// 784.413 us; speedup vs baseline: 1.0638x; 1.0638x over previous
//
#include <hip/hip_runtime.h>
#include <hip/hip_bf16.h>

#define L_SEQ 2048
#define BSZ 2
#define DMODEL 1024
#define NHEAD 16
#define NROWS 4096  // L*BS

typedef __attribute__((ext_vector_type(8))) short bf16x8;
typedef __attribute__((ext_vector_type(4))) float f32x4;
typedef unsigned short u16;
typedef unsigned int u32;

__device__ __forceinline__ u16 f2bf(float x) {
  union { __hip_bfloat16 h; u16 u; } cv;
  cv.h = __float2bfloat16(x);
  return cv.u;
}

__device__ __forceinline__ void async16(void* lds, const void* g) {
  __builtin_amdgcn_global_load_lds(
      (const __attribute__((address_space(1))) void*)g,
      (__attribute__((address_space(3))) void*)lds, 16, 0, 0);
}

// ---------------- converts ----------------
__global__ __launch_bounds__(256) void cvt_kernel(const float* __restrict__ s,
                                                  u16* __restrict__ d, int n) {
  int i = (blockIdx.x * 256 + threadIdx.x) * 4;
  if (i >= n) return;
  float4 v = *(const float4*)(s + i);
  ushort4 o;
  o.x = f2bf(v.x); o.y = f2bf(v.y); o.z = f2bf(v.z); o.w = f2bf(v.w);
  *(ushort4*)(d + i) = o;
}

// V (4096x1024 f32) -> right half of combined (4096x2048 bf16)
__global__ __launch_bounds__(256) void cvtV_kernel(const float* __restrict__ s,
                                                   u16* __restrict__ comb) {
  int i = (blockIdx.x * 256 + threadIdx.x) * 4;
  if (i >= NROWS * DMODEL) return;
  int r = i >> 10, c = i & 1023;
  float4 v = *(const float4*)(s + i);
  ushort4 o;
  o.x = f2bf(v.x); o.y = f2bf(v.y); o.z = f2bf(v.z); o.w = f2bf(v.w);
  *(ushort4*)(comb + (size_t)r * 2048 + 1024 + c) = o;
}

// V [L][BS][1024] f32 -> Vt[bh=32][d=64][L=2048] bf16 (per-head transpose)
__global__ __launch_bounds__(256) void transposeV_kernel(const float* __restrict__ V,
                                                         u16* __restrict__ vt) {
  __shared__ u16 T[64][80];  // [d][key], padded row (160B, 16B-aligned)
  const int tid = threadIdx.x;
  const int k0 = blockIdx.x * 64;
  const int bh = blockIdx.y;
  const int b = bh >> 4, h = bh & 15;
#pragma unroll
  for (int u = 0; u < 4; ++u) {
    int key = u * 16 + (tid >> 4);
    int d4 = (tid & 15) * 4;
    float4 v = *(const float4*)(V + ((size_t)(k0 + key) * 2 + b) * 1024 + h * 64 + d4);
    T[d4 + 0][key] = f2bf(v.x);
    T[d4 + 1][key] = f2bf(v.y);
    T[d4 + 2][key] = f2bf(v.z);
    T[d4 + 3][key] = f2bf(v.w);
  }
  __syncthreads();
  int d = tid >> 2, kq = (tid & 3) * 16;
  uint4 lo = *(const uint4*)&T[d][kq];
  uint4 hi = *(const uint4*)&T[d][kq + 8];
  u16* dst = vt + ((size_t)bh * 64 + d) * 2048 + k0 + kq;
  *(uint4*)dst = lo;
  *(uint4*)(dst + 8) = hi;
}

// ---------------- GEMM: C(MxN) = A(MxK) @ B(NxK)^T, bf16 in, fp32 acc -------
__global__ __launch_bounds__(256) void gemm_bt(
    const u16* __restrict__ A, const u16* __restrict__ B,
    const float* __restrict__ bias, float scale,
    u16* __restrict__ Cb, float* __restrict__ Cf, float* __restrict__ ksq_out,
    int M, int N, int K) {
  __shared__ u16 As[128 * 64];
  __shared__ u16 Bs[128 * 64];
  const int tid = threadIdx.x;
  const int w = tid >> 6, lane = tid & 63;
  const int quad = lane >> 4, m16 = lane & 15;
  const int wr = w >> 1, wc = w & 1;
  const int m0 = blockIdx.y * 128, n0 = blockIdx.x * 128;
  f32x4 acc[4][4] = {};

  for (int kt = 0; kt < K; kt += 64) {
    __syncthreads();
#pragma unroll
    for (int j = 0; j < 4; ++j) {
      int chunk = (w * 4 + j) * 64 + lane;  // 0..1023, 16B each
      int row = chunk >> 3, kc = chunk & 7;
      async16(As + (size_t)(w * 4 + j) * 512,
              A + (size_t)(m0 + row) * K + kt + kc * 8);
      async16(Bs + (size_t)(w * 4 + j) * 512,
              B + (size_t)(n0 + row) * K + kt + kc * 8);
    }
    __syncthreads();
#pragma unroll
    for (int kk = 0; kk < 2; ++kk) {
      bf16x8 af[4], bfr[4];
#pragma unroll
      for (int i = 0; i < 4; ++i)
        af[i] = *(const bf16x8*)(As + (wr * 64 + i * 16 + m16) * 64 + kk * 32 + quad * 8);
#pragma unroll
      for (int j = 0; j < 4; ++j)
        bfr[j] = *(const bf16x8*)(Bs + (wc * 64 + j * 16 + m16) * 64 + kk * 32 + quad * 8);
#pragma unroll
      for (int i = 0; i < 4; ++i)
#pragma unroll
        for (int j = 0; j < 4; ++j)
          acc[i][j] = __builtin_amdgcn_mfma_f32_16x16x32_bf16(af[i], bfr[j], acc[i][j], 0, 0, 0);
    }
  }

#pragma unroll
  for (int i = 0; i < 4; ++i) {
    int R0 = m0 + wr * 64 + i * 16 + quad * 4;
    float ksq_part[4] = {0.f, 0.f, 0.f, 0.f};
#pragma unroll
    for (int j = 0; j < 4; ++j) {
      int C = n0 + wc * 64 + j * 16 + m16;
      float bv = bias ? bias[C] : 0.0f;
#pragma unroll
      for (int r = 0; r < 4; ++r) {
        float v = (acc[i][j][r] + bv) * scale;
        size_t idx = (size_t)(R0 + r) * N + C;
        if (Cb) Cb[idx] = f2bf(v);
        if (Cf) Cf[idx] = v;
        if (ksq_out) ksq_part[r] += v * v;
      }
    }
    if (ksq_out) {
#pragma unroll
      for (int r = 0; r < 4; ++r) {
        float t = ksq_part[r];
        t += __shfl_xor(t, 1); t += __shfl_xor(t, 2);
        t += __shfl_xor(t, 4); t += __shfl_xor(t, 8);
        if (m16 == 0) {
          int R = R0 + r;
          int bb = R & 1, l = R >> 1;
          int h = (n0 + wc * 64) >> 6;
          ksq_out[(size_t)(bb * NHEAD + h) * L_SEQ + l] = t;
        }
      }
    }
  }
}

// ---------------- attention ----------------
// Block = 128 q-rows of one (b,h); 4 waves x 32 q (2 qsets of 16).
// LDS map (dynamic, 80 KB): [0,16K) KB0 | [16K,32K) KB1 | [32K,48K) VB0 |
//   [48K,64K) VB1 | [64K,80K) Ps (4 waves x 4 KB).
// K tiles: 128 keys, pair-packed LDS rows [kp=key/2][16 granules]:
//   slot (kp,g) holds global (key = kp*2 + (gs>>3), dgran = gs&7), gs = g^(kp&15).
// V tiles: VB[d][128 keys], slot granule g holds key-granule gs = g^(d&15).
// Ps (wave-private) [16 q][128 k], col-granule ^= row.
// All LDS reads/writes conflict-free (16 granule-cols, 4 lanes each).
// One __syncthreads per tile-iter; K/V double-buffered, prefetch t+1 during t.
__global__ __launch_bounds__(256, 2) void attn_kernel(
    const u16* __restrict__ qp, const u16* __restrict__ kp,
    const float* __restrict__ ksqg, const u16* __restrict__ vt,
    u16* __restrict__ comb_o, float* __restrict__ attn_out) {
  extern __shared__ u16 smem[];

  const int tid = threadIdx.x;
  const int w = tid >> 6, lane = tid & 63;
  const int quad = lane >> 4, m16 = lane & 15;
  const int id = blockIdx.x;                    // 0..511
  const int wg = (id & 7) * 64 + (id >> 3);     // XCD-chunked: 4 heads per XCD
  const int bh = wg >> 4, qt = wg & 15;
  const int b = bh >> 4, h = bh & 15;
  const int q0 = qt * 128;
  u16* psw = smem + 32768 + w * 2048;

  // ---- prologue: stage Q -> KB1, K(0) -> KB0, ksq(0) -> regs
#pragma unroll
  for (int u = 0; u < 4; ++u) {
    int base = u * 256 + w * 64;
    int chunk = base + lane;
    int kpr = chunk >> 4, g = chunk & 15;
    int gs = g ^ (kpr & 15);
    int qrow = q0 + kpr * 2 + (gs >> 3);
    int dg = gs & 7;
    async16(smem + 8192 + base * 8, qp + ((size_t)(qrow * 2 + b)) * 1024 + h * 64 + dg * 8);
  }
#pragma unroll
  for (int u = 0; u < 4; ++u) {
    int base = u * 256 + w * 64;
    int chunk = base + lane;
    int kpr = chunk >> 4, g = chunk & 15;
    int gs = g ^ (kpr & 15);
    int key = kpr * 2 + (gs >> 3);
    int dg = gs & 7;
    async16(smem + base * 8, kp + ((size_t)(key * 2 + b)) * 1024 + h * 64 + dg * 8);
  }
  float kqc[8], kqn[8];
#pragma unroll
  for (int j = 0; j < 8; ++j) kqc[j] = ksqg[(size_t)bh * L_SEQ + j * 16 + m16];
  __syncthreads();

  bf16x8 aq[2][2];
#pragma unroll
  for (int qs = 0; qs < 2; ++qs)
#pragma unroll
    for (int hf = 0; hf < 2; ++hf) {
      int rowloc = w * 32 + qs * 16 + m16;
      int kpr = rowloc >> 1, hi2 = rowloc & 1;
      int gs = hi2 * 8 + hf * 4 + quad;
      int g = gs ^ (kpr & 15);
      aq[qs][hf] = *(const bf16x8*)(smem + 8192 + kpr * 128 + g * 8);
    }
  __syncthreads();  // Q consumed; KB1 reusable

  // ---- pass A: row sums of exp(s), s = qp.kp - ksq (bounded small, no max)
  float ls[2][4] = {};
  for (int t = 0; t < 16; ++t) {
    const int cur = t & 1;
    const u16* kb = smem + (cur ? 8192 : 0);
    u16* kbn = smem + (cur ? 0 : 8192);
    if (t < 15) {
#pragma unroll
      for (int u = 0; u < 4; ++u) {
        int base = u * 256 + w * 64;
        int chunk = base + lane;
        int kpr = chunk >> 4, g = chunk & 15;
        int gs = g ^ (kpr & 15);
        int key = (t + 1) * 128 + kpr * 2 + (gs >> 3);
        int dg = gs & 7;
        async16(kbn + base * 8, kp + ((size_t)(key * 2 + b)) * 1024 + h * 64 + dg * 8);
      }
#pragma unroll
      for (int j = 0; j < 8; ++j)
        kqn[j] = ksqg[(size_t)bh * L_SEQ + (t + 1) * 128 + j * 16 + m16];
    }
#pragma unroll
    for (int j = 0; j < 8; ++j) {
      int kpr = j * 8 + (m16 >> 1);
      int hi2 = m16 & 1;
      int g0 = (hi2 * 8 + quad) ^ (kpr & 15);
      int g1 = (hi2 * 8 + 4 + quad) ^ (kpr & 15);
      bf16x8 bk0 = *(const bf16x8*)(kb + kpr * 128 + g0 * 8);
      bf16x8 bk1 = *(const bf16x8*)(kb + kpr * 128 + g1 * 8);
      f32x4 s0 = {0.f, 0.f, 0.f, 0.f}, s1 = {0.f, 0.f, 0.f, 0.f};
      __builtin_amdgcn_s_setprio(1);
      s0 = __builtin_amdgcn_mfma_f32_16x16x32_bf16(aq[0][0], bk0, s0, 0, 0, 0);
      s0 = __builtin_amdgcn_mfma_f32_16x16x32_bf16(aq[0][1], bk1, s0, 0, 0, 0);
      s1 = __builtin_amdgcn_mfma_f32_16x16x32_bf16(aq[1][0], bk0, s1, 0, 0, 0);
      s1 = __builtin_amdgcn_mfma_f32_16x16x32_bf16(aq[1][1], bk1, s1, 0, 0, 0);
      __builtin_amdgcn_s_setprio(0);
      float kq = kqc[j];
#pragma unroll
      for (int r = 0; r < 4; ++r) {
        ls[0][r] += __expf(s0[r] - kq);
        ls[1][r] += __expf(s1[r] - kq);
      }
    }
    if (t < 15) {
#pragma unroll
      for (int j = 0; j < 8; ++j) kqc[j] = kqn[j];
    }
    __syncthreads();
  }
  float linv[2][4];
#pragma unroll
  for (int qs = 0; qs < 2; ++qs)
#pragma unroll
    for (int r = 0; r < 4; ++r) {
      float tt = ls[qs][r];
      tt += __shfl_xor(tt, 1); tt += __shfl_xor(tt, 2);
      tt += __shfl_xor(tt, 4); tt += __shfl_xor(tt, 8);
      linv[qs][r] = 1.0f / tt;
    }

  // ---- pass B prologue: K(0) -> KB0, V(0) -> VB0, ksq(0) -> regs
#pragma unroll
  for (int u = 0; u < 4; ++u) {
    int base = u * 256 + w * 64;
    int chunk = base + lane;
    int kpr = chunk >> 4, g = chunk & 15;
    int gs = g ^ (kpr & 15);
    int key = kpr * 2 + (gs >> 3);
    int dg = gs & 7;
    async16(smem + base * 8, kp + ((size_t)(key * 2 + b)) * 1024 + h * 64 + dg * 8);
  }
#pragma unroll
  for (int u = 0; u < 4; ++u) {
    int base = u * 256 + w * 64;
    int chunk = base + lane;
    int d = chunk >> 4, g = chunk & 15;
    int gs = g ^ (d & 15);
    async16(smem + 16384 + base * 8, vt + ((size_t)bh * 64 + d) * 2048 + gs * 8);
  }
#pragma unroll
  for (int j = 0; j < 8; ++j) kqc[j] = ksqg[(size_t)bh * L_SEQ + j * 16 + m16];
  __syncthreads();

  // ---- pass B: recompute S, write attn, P@V
  f32x4 o[2][4] = {};
  for (int t = 0; t < 16; ++t) {
    const int cur = t & 1;
    const u16* kb = smem + (cur ? 8192 : 0);
    const u16* vb = smem + 16384 + (cur ? 8192 : 0);
    u16* kbn = smem + (cur ? 0 : 8192);
    u16* vbn = smem + 16384 + (cur ? 0 : 8192);
    if (t < 15) {
#pragma unroll
      for (int u = 0; u < 4; ++u) {
        int base = u * 256 + w * 64;
        int chunk = base + lane;
        int kpr = chunk >> 4, g = chunk & 15;
        int gs = g ^ (kpr & 15);
        int key = (t + 1) * 128 + kpr * 2 + (gs >> 3);
        int dg = gs & 7;
        async16(kbn + base * 8, kp + ((size_t)(key * 2 + b)) * 1024 + h * 64 + dg * 8);
      }
#pragma unroll
      for (int u = 0; u < 4; ++u) {
        int base = u * 256 + w * 64;
        int chunk = base + lane;
        int d = chunk >> 4, g = chunk & 15;
        int gs = g ^ (d & 15);
        async16(vbn + base * 8,
                vt + ((size_t)bh * 64 + d) * 2048 + (t + 1) * 128 + gs * 8);
      }
#pragma unroll
      for (int j = 0; j < 8; ++j)
        kqn[j] = ksqg[(size_t)bh * L_SEQ + (t + 1) * 128 + j * 16 + m16];
    }
#pragma unroll
    for (int qs = 0; qs < 2; ++qs) {
#pragma unroll
      for (int j = 0; j < 8; ++j) {
        int kpr = j * 8 + (m16 >> 1);
        int hi2 = m16 & 1;
        int g0 = (hi2 * 8 + quad) ^ (kpr & 15);
        int g1 = (hi2 * 8 + 4 + quad) ^ (kpr & 15);
        bf16x8 bk0 = *(const bf16x8*)(kb + kpr * 128 + g0 * 8);
        bf16x8 bk1 = *(const bf16x8*)(kb + kpr * 128 + g1 * 8);
        f32x4 s = {0.f, 0.f, 0.f, 0.f};
        s = __builtin_amdgcn_mfma_f32_16x16x32_bf16(aq[qs][0], bk0, s, 0, 0, 0);
        s = __builtin_amdgcn_mfma_f32_16x16x32_bf16(aq[qs][1], bk1, s, 0, 0, 0);
        float kq = kqc[j];
        size_t abase = ((size_t)bh * L_SEQ + q0 + w * 32 + qs * 16 + quad * 4) * L_SEQ +
                       t * 128 + j * 16 + m16;
#pragma unroll
        for (int r = 0; r < 4; ++r) {
          float p = __expf(s[r] - kq) * linv[qs][r];
          attn_out[abase + (size_t)r * L_SEQ] = p;
          int row = quad * 4 + r;
          int gw = (j * 2 + (m16 >> 3)) ^ row;
          psw[row * 128 + gw * 8 + (m16 & 7)] = f2bf(p);
        }
      }
      __builtin_amdgcn_s_setprio(1);
#pragma unroll
      for (int kk = 0; kk < 4; ++kk) {
        bf16x8 pa = *(const bf16x8*)(psw + m16 * 128 + (((kk * 4 + quad) ^ m16)) * 8);
#pragma unroll
        for (int j2 = 0; j2 < 4; ++j2) {
          int d = j2 * 16 + m16;
          bf16x8 bv = *(const bf16x8*)(vb + d * 128 + (((kk * 4 + quad) ^ m16)) * 8);
          o[qs][j2] = __builtin_amdgcn_mfma_f32_16x16x32_bf16(pa, bv, o[qs][j2], 0, 0, 0);
        }
      }
      __builtin_amdgcn_s_setprio(0);
    }
    if (t < 15) {
#pragma unroll
      for (int j = 0; j < 8; ++j) kqc[j] = kqn[j];
    }
    __syncthreads();
  }

#pragma unroll
  for (int qs = 0; qs < 2; ++qs)
#pragma unroll
    for (int j2 = 0; j2 < 4; ++j2)
#pragma unroll
      for (int r = 0; r < 4; ++r) {
        int qrow = q0 + w * 32 + qs * 16 + quad * 4 + r;
        comb_o[(size_t)(qrow * 2 + b) * 2048 + h * 64 + j2 * 16 + m16] = f2bf(o[qs][j2][r]);
      }
}

extern "C" void kernel_launch(void* const* d_in, const int* in_sizes, int n_in,
                              void* d_out, int out_size, void* d_ws, size_t ws_size,
                              hipStream_t stream) {
  const float* Q  = (const float*)d_in[0];
  const float* K  = (const float*)d_in[1];
  const float* V  = (const float*)d_in[2];
  const float* WQ = (const float*)d_in[3];
  const float* bQ = (const float*)d_in[4];
  const float* WK = (const float*)d_in[5];
  const float* bK = (const float*)d_in[6];
  const float* Wp = (const float*)d_in[7];
  const float* bp = (const float*)d_in[8];
  float* proj_out = (float*)d_out;
  float* attn_out = proj_out + (size_t)NROWS * DMODEL;

  char* ws = (char*)d_ws;
  const size_t MB = 1u << 20;
  u16* Qb   = (u16*)(ws + 0 * MB);    // 8 MB (reused as Vt after QP gemm)
  u16* Kb   = (u16*)(ws + 8 * MB);    // 8 MB
  u16* WQb  = (u16*)(ws + 16 * MB);   // 2 MB
  u16* WKb  = (u16*)(ws + 18 * MB);   // 2 MB
  u16* Wpb  = (u16*)(ws + 20 * MB);   // 4 MB
  u16* qpb  = (u16*)(ws + 24 * MB);   // 8 MB (pre-scaled by 0.25)
  u16* kpb  = (u16*)(ws + 32 * MB);   // 8 MB
  u16* comb = (u16*)(ws + 40 * MB);   // 16 MB (4096x2048: [attn_out | V])
  float* ksqb = (float*)(ws + 56 * MB);  // 256 KB
  u16* Vt = Qb;  // 8 MB: [32 bh][64 d][2048 keys] bf16

  cvt_kernel<<<4096, 256, 0, stream>>>(Q, Qb, NROWS * DMODEL);
  cvt_kernel<<<4096, 256, 0, stream>>>(K, Kb, NROWS * DMODEL);
  cvt_kernel<<<1024, 256, 0, stream>>>(WQ, WQb, DMODEL * DMODEL);
  cvt_kernel<<<1024, 256, 0, stream>>>(WK, WKb, DMODEL * DMODEL);
  cvt_kernel<<<2048, 256, 0, stream>>>(Wp, Wpb, DMODEL * 2 * DMODEL);
  cvtV_kernel<<<4096, 256, 0, stream>>>(V, comb);

  // qp = 0.25*(Q @ WQ^T + bQ)   [score = qp.kp - ksq]
  gemm_bt<<<dim3(8, 32), 256, 0, stream>>>(Qb, WQb, bQ, 0.25f, qpb, nullptr, nullptr,
                                           NROWS, DMODEL, DMODEL);
  // kp = K @ WK^T + bK, plus fp32 ksq per (b,h,l)
  gemm_bt<<<dim3(8, 32), 256, 0, stream>>>(Kb, WKb, bK, 1.0f, kpb, nullptr, ksqb,
                                           NROWS, DMODEL, DMODEL);
  // V per-head transpose into the (now dead) Qb region
  transposeV_kernel<<<dim3(32, 32), 256, 0, stream>>>(V, Vt);

  (void)hipFuncSetAttribute(reinterpret_cast<const void*>(attn_kernel),
                            hipFuncAttributeMaxDynamicSharedMemorySize, 81920);
  attn_kernel<<<512, 256, 81920, stream>>>(qpb, kpb, ksqb, Vt, comb, attn_out);
  // proj = [out|V] @ Wp^T + bp
  gemm_bt<<<dim3(8, 32), 256, 0, stream>>>(comb, Wpb, bp, 1.0f, nullptr, proj_out, nullptr,
                                           NROWS, DMODEL, 2 * DMODEL);
}